// Round 14
// baseline (46.284 us; speedup 1.0000x reference)
//
#include <hip/hip_runtime.h>
#include <stdint.h>

// Spatial transformer: batched dense-displacement trilinear warp.
// z-marching ring-buffer LDS pipeline (r10 frame) + counted-vmcnt step barrier.
// vol: [B=2, D=128, H=192, W=192, 1] f32
// trf: [B=2, D=128, H=192, W=192, 3] f32 (displacement along z,y,x)
// out: [B=2, D=128, H=192, W=192, 1] f32

#define BD 128
#define BH 192
#define BW 192
#define DHW (BD*BH*BW)
#define NB 2

// xy tile 16x8, block marches 4 z-steps of 8 -> 4096 voxels/block
#define TX 16
#define TY 8
#define NTX (BW/TX)                 // 12
#define NTY (BH/TY)                 // 24
#define NZB 4                       // z-chunks (of 32) per volume
#define NSTEPB 4                    // steps per block
#define NBLK (NTX*NTY*NZB*NB)       // 2304 (%8==0)
#define NXCD 8

// staged slab: x 32 [tx-8..tx+23] * y 16 [ty-4..ty+11], one z = 512 floats = 2KB
// ring of 24 slabs (z mod 24) = 48KB -> 3 blocks/CU.
// alive at step k: window [8k-4, 8k+11] + prefetch [8k+12, 8k+19] = 24 distinct
// mod 24; prefetch slots == slots of slabs [8k-12, 8k-5], retired at step k-1.
#define SXW 32
#define SYW 16
#define SLAB (SXW*SYW)              // 512 floats
#define RING 24
#define LDSF (RING*SLAB)            // 12288 floats = 49152 B

typedef float f4v __attribute__((ext_vector_type(4)));

__device__ __forceinline__ int mod24(int z) {
    return (int)((unsigned)z % 24u);   // compiler magic-div (r9 hand-magic was wrong)
}

// Counted-vmcnt step barrier (T4): per-step VMEM issue order is
// [4x global_load_lds prefetch][3x trf load][1x nt store]; vmcnt retires
// strictly in issue order, so draining to <=4 outstanding guarantees the
// prefetch chunks landed in LDS while trf loads / the store stay in flight.
#define STEP_BARRIER() do {                                            \
    asm volatile("s_waitcnt vmcnt(4) lgkmcnt(0)" ::: "memory");        \
    __builtin_amdgcn_s_barrier();                                      \
} while (0)

__global__ __launch_bounds__(256, 3) void st_warp_kernel(
    const float* __restrict__ vol,
    const float* __restrict__ trf,
    float* __restrict__ out)
{
    __shared__ __align__(16) float lds[LDSF];

    // XCD-chunked swizzle (2304 % 8 == 0 -> bijective)
    const int bid = blockIdx.x;
    const int swz = (bid % NXCD) * (NBLK / NXCD) + bid / NXCD;
    int t = swz;
    const int txi = t % NTX; t /= NTX;
    const int tyi = t % NTY; t /= NTY;
    const int kzb = t % NZB; t /= NZB;
    const int b   = t;
    const int tx = txi*TX, ty = tyi*TY;
    const int zA = kzb * (NSTEPB*8);            // first output z of this block

    const int sx = min(max(tx - 8, 0), BW - SXW);   // multiple of 4 -> 16B aligned
    const int sy = min(max(ty - 4, 0), BH - SYW);

    const int tid = (int)threadIdx.x;
    const float* volb = vol + (size_t)b * DHW;

    // thread's voxel-quad within a step: x = Xb..Xb+3, y = Y, z = zstep + zb
    const int xq = tid & 3;
    const int yb = (tid >> 2) & 7;
    const int zb = tid >> 5;
    const int Y  = ty + yb;
    const int Xb = tx + xq*4;
    const f4v* trf4 = (const f4v*)trf;

    // ---- stage nslab slabs [zfirst, zfirst+nslab) into ring slots (z mod 24) ----
    // chunk f (16B): slab f>>7, within-slab chunk s=f&127 (yi=s>>3, c=s&7).
    // wave-runs of 64 chunks never straddle a 128-chunk slab -> slot uniform per
    // wave -> LDS dest stays base + lane*16 (linear, required by gload_lds).
    auto stage = [&](int zfirst, int nslab) {
        const int nch = nslab << 7;
        for (int it = 0; it*256 < nch; ++it) {
            const int f = tid + it*256;
            if (f < nch) {
                const int z  = zfirst + (f >> 7);
                const int s  = f & 127;
                const int yi = s >> 3;
                const int c  = s & 7;
                const int slot = mod24(z);
                const float* g = volb + ((size_t)(z*BH + sy + yi))*BW + sx + (c<<2);
                __builtin_amdgcn_global_load_lds(
                    (const __attribute__((address_space(1))) void*)g,
                    (__attribute__((address_space(3))) void*)&lds[(slot<<9) + (s<<2)],
                    16, 0, 0);
            }
        }
    };

    auto load_trf = [&](int ZS, f4v& TA, f4v& TB, f4v& TC) {
        const size_t rowf4 = ((size_t)((b*BD + ZS + zb)*BH + Y)*BW + tx) * 3 / 4;
        TA = trf4[rowf4 + 3*xq + 0];
        TB = trf4[rowf4 + 3*xq + 1];
        TC = trf4[rowf4 + 3*xq + 2];
    };

    // ---- compute one step: 4 voxels at z = ZS + zb, from ring-resident slabs ----
    auto compute_vals = [&](int ZS, f4v tA, f4v tB, f4v tC) -> f4v {
        const int Z   = ZS + zb;
        const int wlo = max(0, ZS - 4);
        const int whi = min(BD - 1, ZS + 11);
        const float dzs[4] = {tA.x, tA.w, tB.z, tC.y};
        const float dys[4] = {tA.y, tB.x, tB.w, tC.z};
        const float dxs[4] = {tA.z, tB.y, tC.x, tC.w};
        float res[4];
#pragma unroll
        for (int jj = 0; jj < 4; ++jj) {
            // high-clamp only; low-side out-of-range fails inwin -> fallback
            // clamps the integer corners (exact: colliding corners make the
            // weight's operand cancel, matching the reference).
            float cz = fminf((float)Z + dzs[jj], (float)(BD-1));
            float cy = fminf((float)Y + dys[jj], (float)(BH-1));
            float cx = fminf((float)(Xb+jj) + dxs[jj], (float)(BW-1));
            float fz = floorf(cz), fy = floorf(cy), fx = floorf(cx);
            int z0 = (int)fz, y0 = (int)fy, x0 = (int)fx;
            int z1 = min(z0+1, BD-1);
            int y1 = min(y0+1, BH-1);
            int x1 = min(x0+1, BW-1);
            float wz = cz - fz, wy = cy - fy, wx = cx - fx;
            float v000,v001,v010,v011,v100,v101,v110,v111;
            bool inwin = (x0 >= sx) & (x1 <= sx+SXW-1) & (y0 >= sy) & (y1 <= sy+SYW-1)
                       & (z0 >= wlo) & (z1 <= whi);
            if (inwin) {
                const int xi  = x0 - sx;
                const int xiA = min(xi, SXW-2);     // x==191 edge: read pair, select
                const bool lo = xi < SXW-1;
                int sl0 = mod24(z0);
                int sl1 = sl0 + 1;
                sl1 = (sl1 == RING) ? 0 : sl1;
                sl1 = (z1 == z0) ? sl0 : sl1;       // z clamped at top edge
                const int yt0 = (y0 - sy) << 5, yt1 = (y1 - sy) << 5;
                const int rA = (sl0<<9) + yt0 + xiA;
                const int rB = (sl0<<9) + yt1 + xiA;
                const int rC = (sl1<<9) + yt0 + xiA;
                const int rD = (sl1<<9) + yt1 + xiA;
                float a00 = lds[rA], b00 = lds[rA+1];
                float a01 = lds[rB], b01 = lds[rB+1];
                float a10 = lds[rC], b10 = lds[rC+1];
                float a11 = lds[rD], b11 = lds[rD+1];
                v000 = lo ? a00 : b00;  v001 = b00;
                v010 = lo ? a01 : b01;  v011 = b01;
                v100 = lo ? a10 : b10;  v101 = b10;
                v110 = lo ? a11 : b11;  v111 = b11;
            } else {
                const int z0c = max(z0, 0), z1c = max(z1, 0);
                const int y0c = max(y0, 0), y1c = max(y1, 0);
                const int x0c = max(x0, 0), x1c = max(x1, 0);
                const float* p00 = volb + ((size_t)z0c*BH + y0c)*BW;
                const float* p01 = volb + ((size_t)z0c*BH + y1c)*BW;
                const float* p10 = volb + ((size_t)z1c*BH + y0c)*BW;
                const float* p11 = volb + ((size_t)z1c*BH + y1c)*BW;
                v000 = p00[x0c]; v001 = p00[x1c];
                v010 = p01[x0c]; v011 = p01[x1c];
                v100 = p10[x0c]; v101 = p10[x1c];
                v110 = p11[x0c]; v111 = p11[x1c];
            }
            float c00 = v000 + wx*(v001-v000);
            float c01 = v010 + wx*(v011-v010);
            float c10 = v100 + wx*(v101-v100);
            float c11 = v110 + wx*(v111-v110);
            float c0  = c00 + wy*(c01-c00);
            float c1  = c10 + wy*(c11-c10);
            res[jj]   = c0 + wz*(c1-c0);
        }
        f4v r = {res[0], res[1], res[2], res[3]};
        return r;
    };

    // ---------------- pipeline ----------------
    f4v TA[2], TB[2], TC[2];
    // prologue: first window [max(0,zA-4), zA+11] + trf for step 0 (full drain)
    stage(max(0, zA - 4), (zA == 0) ? 12 : 16);
    load_trf(zA, TA[0], TB[0], TC[0]);
    __syncthreads();

#pragma unroll
    for (int k = 0; k < NSTEPB; ++k) {
        const int ZS = zA + k*8;
        if (k + 1 < NSTEPB) {
            const int zn = ZS + 12;                 // new slabs for window k+1
            if (zn < BD) stage(zn, min(8, BD - zn));
            load_trf(ZS + 8, TA[(k+1)&1], TB[(k+1)&1], TC[(k+1)&1]);
        }
        f4v r = compute_vals(ZS, TA[k&1], TB[k&1], TC[k&1]);
        // store issued LAST (newest VMEM op) so the counted barrier lets it
        // ride across; it retires under the next step's compute.
        const size_t of4 = ((size_t)((b*BD + ZS + zb)*BH + Y)*BW + Xb) / 4;
        __builtin_nontemporal_store(r, &((f4v*)out)[of4]);
        STEP_BARRIER();
    }
}

extern "C" void kernel_launch(void* const* d_in, const int* in_sizes, int n_in,
                              void* d_out, int out_size, void* d_ws, size_t ws_size,
                              hipStream_t stream) {
    const float* vol = (const float*)d_in[0];
    const float* trf = (const float*)d_in[1];
    float* out = (float*)d_out;

    st_warp_kernel<<<dim3(NBLK), dim3(256), 0, stream>>>(vol, trf, out);
}

// Round 15
// 44.054 us; speedup vs baseline: 1.0506x; 1.0506x over previous
//
#include <hip/hip_runtime.h>
#include <stdint.h>

// Spatial transformer: batched dense-displacement trilinear warp.
// z-marching ring pipeline, RING=16 (masked slots), 32KB LDS -> 5 blocks/CU.
// vol: [B=2, D=128, H=192, W=192, 1] f32
// trf: [B=2, D=128, H=192, W=192, 3] f32 (displacement along z,y,x)
// out: [B=2, D=128, H=192, W=192, 1] f32

#define BD 128
#define BH 192
#define BW 192
#define DHW (BD*BH*BW)
#define NB 2

// xy tile 16x8, block marches 8 z-steps of 4 -> 32 z, 4096 voxels/block
#define TX 16
#define TY 8
#define NTX (BW/TX)                 // 12
#define NTY (BH/TY)                 // 24
#define ZSTEP 4
#define NSTEPB 8
#define BLKZ (ZSTEP*NSTEPB)         // 32
#define NZB (BD/BLKZ)               // 4
#define NBLK (NTX*NTY*NZB*NB)       // 2304 (%8==0)
#define NXCD 8

// staged slab: x 32 [tx-8..tx+23] * y 16 [ty-4..ty+11], one z = 512 floats = 2KB
// ring of 16 slabs (slot = z & 15) = 32KB -> 5 blocks/CU (the occupancy lever).
// step k (ZS=zA+4k): window [ZS-4, ZS+7] (12 slabs) + prefetch [ZS+8, ZS+11] (4)
// = 16 distinct mod 16. Prefetch slots == slots of z-16 in [ZS-8, ZS-5]: last
// readable in step k-1's window, and the step-(k-1) barrier orders those reads
// before this step's overwrite.
#define SXW 32
#define SYW 16
#define SLAB (SXW*SYW)              // 512 floats = 128 chunks of 16B
#define RING 16
#define LDSF (RING*SLAB)            // 8192 floats = 32768 B

typedef float f4v __attribute__((ext_vector_type(4)));
typedef float f2v __attribute__((ext_vector_type(2)));

__global__ __launch_bounds__(256, 5) void st_warp_kernel(
    const float* __restrict__ vol,
    const float* __restrict__ trf,
    float* __restrict__ out)
{
    __shared__ __align__(16) float lds[LDSF];

    // XCD-chunked swizzle (2304 % 8 == 0 -> bijective)
    const int bid = blockIdx.x;
    const int swz = (bid % NXCD) * (NBLK / NXCD) + bid / NXCD;
    int t = swz;
    const int txi = t % NTX; t /= NTX;
    const int tyi = t % NTY; t /= NTY;
    const int kzb = t % NZB; t /= NZB;
    const int b   = t;
    const int tx = txi*TX, ty = tyi*TY;
    const int zA = kzb * BLKZ;                  // first output z of this block

    const int sx = min(max(tx - 8, 0), BW - SXW);   // multiple of 4 -> 16B aligned
    const int sy = min(max(ty - 4, 0), BH - SYW);

    const int tid = (int)threadIdx.x;
    const float* volb = vol + (size_t)b * DHW;

    // thread owns an x-PAIR per step: x = X0, X0+1; 8x8x4 pairs = 256 threads
    const int xp = tid & 7;
    const int yb = (tid >> 3) & 7;
    const int zb = tid >> 6;                    // 0..3, wave-uniform
    const int Y  = ty + yb;
    const int X0 = tx + xp*2;

    // ---- stage nslab slabs [zfirst, zfirst+nslab) into ring slots (z & 15) ----
    // chunk f: slab f>>7, within-slab s=f&127 (yi=s>>3, c=s&7). 128%64==0 ->
    // a wave's 64-chunk run never straddles a slab -> slot uniform per wave ->
    // LDS dest stays base + lane*16 (linear, required by gload_lds).
    auto stage = [&](int zfirst, int nslab) {
        const int nch = nslab << 7;             // always a multiple of 256 here
        for (int it = 0; it*256 < nch; ++it) {
            const int f = tid + it*256;
            if (f < nch) {
                const int z  = zfirst + (f >> 7);
                const int s  = f & 127;
                const int yi = s >> 3;
                const int c  = s & 7;
                const int slot = z & (RING-1);
                const float* g = volb + ((size_t)(z*BH + sy + yi))*BW + sx + (c<<2);
                __builtin_amdgcn_global_load_lds(
                    (const __attribute__((address_space(1))) void*)g,
                    (__attribute__((address_space(3))) void*)&lds[(slot<<9) + (s<<2)],
                    16, 0, 0);
            }
        }
    };

    // trf for the pair at (Z=ZS+zb, Y, X0..X0+1): 6 contiguous floats, 3x float2
    // (float offset 3*X0 is even -> 8B aligned).
    const f2v* t2 = (const f2v*)trf;
    auto load_trf = [&](int ZS, f2v& D0, f2v& D1, f2v& D2) {
        const size_t base2 = (((size_t)((b*BD + ZS + zb)*BH + Y))*BW + X0) * 3 / 2;
        D0 = t2[base2 + 0];     // dz0, dy0
        D1 = t2[base2 + 1];     // dx0, dz1
        D2 = t2[base2 + 2];     // dy1, dx1
    };

    // ---- compute one step: 2 voxels at z = ZS + zb from ring-resident slabs ----
    auto compute_vals = [&](int ZS, f2v D0, f2v D1, f2v D2) -> f2v {
        const int Z   = ZS + zb;
        const int wlo = max(0, ZS - 4);
        const int whi = min(BD - 1, ZS + 7);
        const float dzs[2] = {D0.x, D1.y};
        const float dys[2] = {D0.y, D2.x};
        const float dxs[2] = {D1.x, D2.y};
        float res[2];
#pragma unroll
        for (int jj = 0; jj < 2; ++jj) {
            // high-clamp only; low-side out-of-range fails inwin -> fallback
            // clamps integer corners (exact: colliding corners cancel the weight)
            float cz = fminf((float)Z + dzs[jj], (float)(BD-1));
            float cy = fminf((float)Y + dys[jj], (float)(BH-1));
            float cx = fminf((float)(X0+jj) + dxs[jj], (float)(BW-1));
            float fz = floorf(cz), fy = floorf(cy), fx = floorf(cx);
            int z0 = (int)fz, y0 = (int)fy, x0 = (int)fx;
            int z1 = min(z0+1, BD-1);
            int y1 = min(y0+1, BH-1);
            int x1 = min(x0+1, BW-1);
            float wz = cz - fz, wy = cy - fy, wx = cx - fx;
            float v000,v001,v010,v011,v100,v101,v110,v111;
            bool inwin = (x0 >= sx) & (x1 <= sx+SXW-1) & (y0 >= sy) & (y1 <= sy+SYW-1)
                       & (z0 >= wlo) & (z1 <= whi);
            if (inwin) {
                const int xi  = x0 - sx;
                const int xiA = min(xi, SXW-2);     // x==191 edge: read pair, select
                const bool lo = xi < SXW-1;
                const int sl0 = z0 & (RING-1);
                const int sl1 = z1 & (RING-1);      // z1==z0 at top edge -> same slot
                const int yt0 = (y0 - sy) << 5, yt1 = (y1 - sy) << 5;
                const int rA = (sl0<<9) + yt0 + xiA;
                const int rB = (sl0<<9) + yt1 + xiA;
                const int rC = (sl1<<9) + yt0 + xiA;
                const int rD = (sl1<<9) + yt1 + xiA;
                float a00 = lds[rA], b00 = lds[rA+1];
                float a01 = lds[rB], b01 = lds[rB+1];
                float a10 = lds[rC], b10 = lds[rC+1];
                float a11 = lds[rD], b11 = lds[rD+1];
                v000 = lo ? a00 : b00;  v001 = b00;
                v010 = lo ? a01 : b01;  v011 = b01;
                v100 = lo ? a10 : b10;  v101 = b10;
                v110 = lo ? a11 : b11;  v111 = b11;
            } else {
                const int z0c = max(z0, 0), z1c = max(z1, 0);
                const int y0c = max(y0, 0), y1c = max(y1, 0);
                const int x0c = max(x0, 0), x1c = max(x1, 0);
                const float* p00 = volb + ((size_t)z0c*BH + y0c)*BW;
                const float* p01 = volb + ((size_t)z0c*BH + y1c)*BW;
                const float* p10 = volb + ((size_t)z1c*BH + y0c)*BW;
                const float* p11 = volb + ((size_t)z1c*BH + y1c)*BW;
                v000 = p00[x0c]; v001 = p00[x1c];
                v010 = p01[x0c]; v011 = p01[x1c];
                v100 = p10[x0c]; v101 = p10[x1c];
                v110 = p11[x0c]; v111 = p11[x1c];
            }
            float c00 = v000 + wx*(v001-v000);
            float c01 = v010 + wx*(v011-v010);
            float c10 = v100 + wx*(v101-v100);
            float c11 = v110 + wx*(v111-v110);
            float c0  = c00 + wy*(c01-c00);
            float c1  = c10 + wy*(c11-c10);
            res[jj]   = c0 + wz*(c1-c0);
        }
        f2v r = {res[0], res[1]};
        return r;
    };

    // ---------------- pipeline ----------------
    f2v D0[2], D1[2], D2[2];
    // prologue: first window [max(0,zA-4), zA+7] + trf for step 0 (full drain)
    stage(max(0, zA - 4), (zA == 0) ? 8 : 12);
    load_trf(zA, D0[0], D1[0], D2[0]);
    __syncthreads();

#pragma unroll
    for (int k = 0; k < NSTEPB; ++k) {
        const int ZS = zA + k*ZSTEP;
        if (k + 1 < NSTEPB) {
            const int zn = ZS + 8;                 // new slabs for window k+1
            if (zn < BD) stage(zn, min(4, BD - zn));
            load_trf(ZS + ZSTEP, D0[(k+1)&1], D1[(k+1)&1], D2[(k+1)&1]);
        }
        f2v r = compute_vals(ZS, D0[k&1], D1[k&1], D2[k&1]);
        const size_t of2 = (((size_t)((b*BD + ZS + zb)*BH + Y))*BW + X0) / 2;
        __builtin_nontemporal_store(r, &((f2v*)out)[of2]);  // no-allocate store
        __syncthreads();
    }
}

extern "C" void kernel_launch(void* const* d_in, const int* in_sizes, int n_in,
                              void* d_out, int out_size, void* d_ws, size_t ws_size,
                              hipStream_t stream) {
    const float* vol = (const float*)d_in[0];
    const float* trf = (const float*)d_in[1];
    float* out = (float*)d_out;

    st_warp_kernel<<<dim3(NBLK), dim3(256), 0, stream>>>(vol, trf, out);
}